// Round 19
// baseline (377.106 us; speedup 1.0000x reference)
//
#include <hip/hip_runtime.h>
#include <math.h>

#define NN 10000
#define NE 320000

typedef __attribute__((ext_vector_type(8))) _Float16 h8v;    // 8 f16 (4 VGPRs) MFMA frag
typedef __attribute__((ext_vector_type(4))) float f4v;       // MFMA accumulator

__device__ __forceinline__ short f2h(float f) {
  _Float16 h = (_Float16)f;            // v_cvt_f16_f32 (RNE)
  short s; __builtin_memcpy(&s, &h, 2); return s;
}
// relu(f16a + f16b) on 8 packed f16 lanes: native clang vector arithmetic lowers
// to 4x v_pk_add_f16 + 4x v_pk_max_f16 with FULL register-allocator freedom.
__device__ __forceinline__ uint4 cvt8(uint4 ua, uint4 ub) {
  h8v a, b;
  __builtin_memcpy(&a, &ua, 16);
  __builtin_memcpy(&b, &ub, 16);
  h8v r = a + b;
  r = __builtin_elementwise_max(r, (h8v)(_Float16)0.0f);
  uint4 o; __builtin_memcpy(&o, &r, 16);
  return o;
}

// lgkm-only barrier: orders all LDS traffic; leaves gather prefetches in flight.
__device__ __forceinline__ void barrier_lgkm_only() {
  asm volatile("s_waitcnt lgkmcnt(0)" ::: "memory");
  __builtin_amdgcn_s_barrier();
}

// ================= edge sort by dst (counting sort) =================
__global__ void hist_kernel(const int* __restrict__ ei, int* __restrict__ cnt) {
  int e = blockIdx.x * 256 + threadIdx.x;
  if (e < NE) atomicAdd(&cnt[ei[NE + e]], 1);
}

__global__ void __launch_bounds__(1024)
scan_kernel(const int* __restrict__ cnt, int* __restrict__ cur) {
  __shared__ int part[1024];
  const int t = threadIdx.x;
  const int base = t * 10;
  int local[10];
  int s = 0;
#pragma unroll
  for (int u = 0; u < 10; ++u) {
    int c = (base + u < NN) ? cnt[base + u] : 0;
    local[u] = s; s += c;
  }
  part[t] = s;
  __syncthreads();
  for (int off = 1; off < 1024; off <<= 1) {
    int v = part[t];
    int w = (t >= off) ? part[t - off] : 0;
    __syncthreads();
    part[t] = v + w;
    __syncthreads();
  }
  int excl = (t == 0) ? 0 : part[t - 1];
#pragma unroll
  for (int u = 0; u < 10; ++u)
    if (base + u < NN) cur[base + u] = excl + local[u];
}

__global__ void scatter_kernel(const int* __restrict__ ei, int* __restrict__ cur,
                               int* __restrict__ sSrc, int* __restrict__ sDst) {
  int e = blockIdx.x * 256 + threadIdx.x;
  if (e < NE) {
    int d = ei[NE + e];
    int p = atomicAdd(&cur[d], 1);
    sSrc[p] = ei[e];
    sDst[p] = d;
  }
}

// ================= prep: combined/transposed weights, fp32 -> f16 =================
__global__ void prep_weights(const float* __restrict__ W1a, const float* __restrict__ W1b,
                             const float* __restrict__ W2a, const float* __restrict__ W2b,
                             short* __restrict__ Wp1T, short* __restrict__ Wp2T,
                             short* __restrict__ BTf1, short* __restrict__ BTf2) {
  int i = blockIdx.x * 256 + threadIdx.x;
  if (i < 131072) {                        // Wp1T[j][k], j<1024, k<128
    int j = i >> 7, k = i & 127;
    float v;
    if (j < 512) v = W1a[k * 512 + j] - W1a[(k + 128) * 512 + j];
    else         v = W1a[(k + 128) * 512 + (j - 512)];
    Wp1T[i] = f2h(v);
  } else if (i < 262144) {                 // Wp2T[j][k], j<512, k<256
    int t = i - 131072;
    int j = t >> 8, k = t & 255;
    float v;
    if (j < 256) v = W1b[k * 256 + j] - W1b[(k + 256) * 256 + j];
    else         v = W1b[(k + 256) * 256 + (j - 256)];
    Wp2T[t] = f2h(v);
  } else if (i < 393216) {                 // BTf1: W2a^T fragment layout (NT=256, K=512)
    int t = i - 262144;
    int n = t >> 9, k = t & 511;
    BTf1[(k >> 5) * 8192 + n * 32 + (k & 31)] = f2h(W2a[k * 256 + n]);
  } else if (i < 425984) {                 // BTf2: W2b^T fragment layout (NT=128, K=256)
    int t = i - 393216;
    int n = t >> 8, k = t & 255;
    BTf2[(k >> 5) * 4096 + n * 32 + (k & 31)] = f2h(W2b[k * 128 + n]);
  }
}

// ================= node GEMM: C[NN][Ntot](f16) = A[NN][K](fp32) @ BT^T + bias ===========
// Round-19 change: MT template param (row-tiles of 16 per block). The old 64-row
// blocks gave node_gemm2 only 314 blocks = 1.2 blocks/CU = ~1.2 waves/SIMD — no
// TLP to hide the fp32-load->convert->MFMA latency chain. MT=1 (16-row blocks):
// node1 2500 blocks (10/CU), node2 1250 (5/CU); LDS 8.4KB, acc 16 regs.
// C-write via padded LDS tile (round-18): 32 lanes store one 512B row of uint4.
template<int K, int MT>
__global__ void __launch_bounds__(256)
node_gemm(const float* __restrict__ A, const short* __restrict__ BT,
          const float* __restrict__ bias, int biasLen,
          short* __restrict__ C, int Ntot) {
  constexpr int CTP = 264;                  // LDS pitch (shorts): 16B rows + bank skew
  __shared__ short ct[MT * 16 * CTP];
  const int rowBase = blockIdx.x * (MT * 16);
  const int wave = threadIdx.x >> 6, lane = threadIdx.x & 63;
  const int colBase = blockIdx.y * 256 + wave * 64;
  const int lm = lane & 15, q = lane >> 4;
  f4v acc[MT][4] = {};
  int arow[MT];
#pragma unroll
  for (int mt = 0; mt < MT; ++mt) {
    int r = rowBase + mt * 16 + lm;
    arow[mt] = r < NN ? r : NN - 1;        // clamp; stores guarded below
  }
  for (int kk = 0; kk < K; kk += 32) {
    const int k = kk + q * 8;
    h8v aF[MT], bF[4];
#pragma unroll
    for (int mt = 0; mt < MT; ++mt) {
      const float4* ap = (const float4*)(A + (size_t)arow[mt] * K + k);
      float4 x0 = ap[0], x1 = ap[1];
      h8v t;
      t[0] = (_Float16)x0.x; t[1] = (_Float16)x0.y; t[2] = (_Float16)x0.z; t[3] = (_Float16)x0.w;
      t[4] = (_Float16)x1.x; t[5] = (_Float16)x1.y; t[6] = (_Float16)x1.z; t[7] = (_Float16)x1.w;
      aF[mt] = t;
    }
#pragma unroll
    for (int nt = 0; nt < 4; ++nt)
      bF[nt] = *(const h8v*)(BT + (size_t)(colBase + nt * 16 + lm) * K + k);
#pragma unroll
    for (int mt = 0; mt < MT; ++mt)
#pragma unroll
      for (int nt = 0; nt < 4; ++nt)
        acc[mt][nt] = __builtin_amdgcn_mfma_f32_16x16x32_f16(aF[mt], bF[nt], acc[mt][nt], 0, 0, 0);
  }
  // acc -> LDS tile (wave's 64-col slice)
  const int wc = wave * 64;
#pragma unroll
  for (int nt = 0; nt < 4; ++nt) {
    int col = colBase + nt * 16 + lm;
    float bv = (col < biasLen) ? bias[col] : 0.0f;
#pragma unroll
    for (int mt = 0; mt < MT; ++mt) {
#pragma unroll
      for (int i = 0; i < 4; ++i)
        ct[(mt * 16 + q * 4 + i) * CTP + wc + nt * 16 + lm] = f2h(acc[mt][nt][i] + bv);
    }
  }
  __syncthreads();
  // coalesced stores: 32 lanes cover one 512B row contiguously
  const int cb0 = blockIdx.y * 256;
  const int tid = threadIdx.x;
#pragma unroll
  for (int it = 0; it < 2 * MT; ++it) {
    int lr = it * 8 + (tid >> 5);
    int row = rowBase + lr;
    int chunk = tid & 31;                   // 32 x 16B = 512B per row
    if (row < NN)
      *(uint4*)(C + (size_t)row * Ntot + cb0 + chunk * 8) =
          *(const uint4*)(&ct[lr * CTP + chunk * 8]);
  }
}

// ================= edge GEMM: f16, 256-thread (4-wave) blocks at (256,3) ==============
// Round-13 config exactly (edge1 ~127us; structural floor — occupancy directions,
// prefetch depth, and barrier semantics all falsified in rounds 12/16/17).
template<int K, int NT, int ROWS>
__global__ void __launch_bounds__(256, 3)
edge_gemm_pf(const short* __restrict__ AB, const short* __restrict__ BTf,
             const float* __restrict__ bias,
             const int* __restrict__ sSrc, const int* __restrict__ sDst,
             int* __restrict__ y) {
  constexpr int KT = 64;            // k-tile
  constexpr int KTP = 72;           // LDS pitch (shorts): breaks bank alignment, keeps 16B
  constexpr int TILES = K / KT;
  constexpr int NCG = NT / 64;      // col-groups (4 or 2)
  constexpr int NRG = 4 / NCG;      // row-groups (1 or 2)
  constexpr int CH = ROWS / 32;     // staged chunks per thread (2 or 4)
  constexpr int NTL = 4;            // 64 cols per wave
  static_assert(ROWS == 64 * NRG, "geometry");
  __shared__ __align__(16) short hA[2][ROWS * KTP];
  __shared__ int srcS[ROWS], dstS[ROWS];
  __shared__ int segDst[2][64];     // dst node per segment, per row-group
  __shared__ int segAtm[2][64];     // 1 = boundary dst (atomic), 0 = interior (store)
  __shared__ __align__(4) unsigned char rowSidC[ROWS]; // per-row segment id within group
  __shared__ int segD[2];

  const int tid = threadIdx.x;
  const int eBase = blockIdx.x * ROWS;
  const int wave = tid >> 6, lane = tid & 63, lm = lane & 15, q = lane >> 4;
  const int cg = wave % NCG, rg = wave / NCG;
  const int cBase = cg * 64;
  const int rg64 = rg * 64;

  if (tid < ROWS) { srcS[tid] = sSrc[eBase + tid]; dstS[tid] = sDst[eBase + tid]; }
  __syncthreads();

  // per-thread staging coords: CH chunks (rows r0+32c), fixed column chunk kc0
  const int r0 = tid >> 3, kc0 = (tid & 7) * 8;
  size_t dO[CH], sO[CH];
#pragma unroll
  for (int c = 0; c < CH; ++c) {
    dO[c] = (size_t)dstS[r0 + 32 * c] * (2 * K) + kc0;
    sO[c] = (size_t)srcS[r0 + 32 * c] * (2 * K) + K + kc0;
  }

  // prologue: issue tile-0 gather prefetch FIRST (latency hidden under table build)
  uint4 av[CH], bv[CH];
#pragma unroll
  for (int c = 0; c < CH; ++c) {
    av[c] = *(const uint4*)(AB + dO[c]);
    bv[c] = *(const uint4*)(AB + sO[c]);
  }

  // ---- waves 0..NRG-1: build per-row-group segment tables (consumed in epilogue;
  // visibility guaranteed by the main-loop barriers) ----
  if (tid < NRG * 64) {
    const int w = tid >> 6;          // row-group
    const int r = tid & 63;          // row within group
    const int row = tid;
    int d = dstS[row];
    int prev = (r == 0) ? -1 : dstS[row - 1];
    bool flag = (r == 0) || (d != prev);
    unsigned long long mask = __ballot(flag);
    int Dtot = __popcll(mask);
    int sid = __popcll(mask & (0xFFFFFFFFFFFFFFFFull >> (63 - r))) - 1;
    rowSidC[row] = (unsigned char)sid;
    if (r == 0) segD[w] = Dtot;
    if (flag) {
      int prevOut = (w > 0) ? dstS[w * 64 - 1]
                            : ((eBase > 0) ? sDst[eBase - 1] : -1);
      int nextOut = (w < NRG - 1) ? dstS[(w + 1) * 64]
                                  : ((eBase + ROWS < NE) ? sDst[eBase + ROWS] : -1);
      bool atm = false;
      if (sid == 0 && prevOut == d) atm = true;
      if (sid == Dtot - 1 && nextOut == d) atm = true;
      segDst[w][sid] = d;
      segAtm[w][sid] = atm ? 1 : 0;
    }
  }

  f4v acc[4][NTL] = {};

  for (int t = 0; t < TILES; ++t) {
    // 1. issue s=0 bF loads (fly during convert + barrier)
    h8v bF0[NTL];
#pragma unroll
    for (int nt = 0; nt < NTL; ++nt)
      bF0[nt] = *(const h8v*)(BTf + (size_t)(t * 2) * (NT * 32) +
                              (cBase + nt * 16 + lm) * 32 + q * 8);
    // 2. convert prefetched gathers -> LDS (double-buffered); packed-f16 ops
    short* hbuf = &hA[t & 1][0];
#pragma unroll
    for (int c = 0; c < CH; ++c)
      *(uint4*)(&hbuf[(r0 + 32 * c) * KTP + kc0]) = cvt8(av[c], bv[c]);
    // 3. prefetch next tile's gathers (stay in flight across the lgkm-only barrier)
    if (t + 1 < TILES) {
      const int kn = (t + 1) * KT;
#pragma unroll
      for (int c = 0; c < CH; ++c) {
        av[c] = *(const uint4*)(AB + dO[c] + kn);
        bv[c] = *(const uint4*)(AB + sO[c] + kn);
      }
    }
    barrier_lgkm_only();
    // 4a. s=0 MFMA: aF per-mt from LDS, bF0 from regs
    {
      const int kl = q * 8;
      __builtin_amdgcn_s_setprio(1);
#pragma unroll
      for (int mt = 0; mt < 4; ++mt) {
        h8v aF = *(const h8v*)(&hbuf[(rg64 + mt * 16 + lm) * KTP + kl]);
#pragma unroll
        for (int nt = 0; nt < NTL; ++nt)
          acc[mt][nt] = __builtin_amdgcn_mfma_f32_16x16x32_f16(aF, bF0[nt], acc[mt][nt], 0, 0, 0);
      }
      __builtin_amdgcn_s_setprio(0);
    }
    // 4b. s=1: load bF1 here (keeps bF register footprint at NTL)
    {
      h8v bF1[NTL];
#pragma unroll
      for (int nt = 0; nt < NTL; ++nt)
        bF1[nt] = *(const h8v*)(BTf + (size_t)(t * 2 + 1) * (NT * 32) +
                                (cBase + nt * 16 + lm) * 32 + q * 8);
      const int kl = 32 + q * 8;
      __builtin_amdgcn_s_setprio(1);
#pragma unroll
      for (int mt = 0; mt < 4; ++mt) {
        h8v aF = *(const h8v*)(&hbuf[(rg64 + mt * 16 + lm) * KTP + kl]);
#pragma unroll
        for (int nt = 0; nt < NTL; ++nt)
          acc[mt][nt] = __builtin_amdgcn_mfma_f32_16x16x32_f16(aF, bF1[nt], acc[mt][nt], 0, 0, 0);
      }
      __builtin_amdgcn_s_setprio(0);
    }
  }

  // ---- epilogue: segmented max per column within this wave's row-group ----
  const int D = segD[rg];
  int sid[4][4];
#pragma unroll
  for (int mt = 0; mt < 4; ++mt) {
    unsigned pk = *(const unsigned*)(&rowSidC[rg64 + mt * 16 + q * 4]);  // 4B aligned
#pragma unroll
    for (int i = 0; i < 4; ++i) sid[mt][i] = (int)((pk >> (8 * i)) & 255u);
  }
#pragma unroll
  for (int nt = 0; nt < NTL; ++nt) {
    const int col = cBase + nt * 16 + lm;
    const float bvv = bias[col];
    for (int s = 0; s < D; ++s) {
      float m = -1e30f;
#pragma unroll
      for (int mt = 0; mt < 4; ++mt)
#pragma unroll
        for (int i = 0; i < 4; ++i)
          m = fmaxf(m, sid[mt][i] == s ? acc[mt][nt][i] : -1e30f);
      // reduce across the 4 q-lanes holding this column
      m = fmaxf(m, __shfl_xor(m, 16));
      m = fmaxf(m, __shfl_xor(m, 32));
      if (q == 0) {
        float v = m + bvv;
        int* addr = &y[(size_t)segDst[rg][s] * NT + col];
        if (segAtm[rg][s]) {
          if (v > 0.f) atomicMax(addr, __float_as_int(v));
        } else {
          *addr = __float_as_int(fmaxf(v, 0.f));   // group owns this dst: plain store
        }
      }
    }
  }
}

// ================= head: one wave per node =================
__global__ void __launch_bounds__(64)
head_kernel(const float* __restrict__ y2, const float* __restrict__ W3,
            const float* __restrict__ b3, const float* __restrict__ W4,
            const float* __restrict__ b4, float* __restrict__ out) {
  const int n = blockIdx.x, j = threadIdx.x;
  const float* yr = y2 + (size_t)n * 128;
  float acc = 0.f;
#pragma unroll
  for (int k = 0; k < 128; ++k) acc += yr[k] * W3[k * 64 + j];
  acc += b3[j];
  float h = acc > 0.f ? acc : 0.f;
  float p = h * W4[j];
#pragma unroll
  for (int off = 32; off; off >>= 1) p += __shfl_down(p, off);
  if (j == 0) {
    float z = p + b4[0];
    out[n] = 1.f / (1.f + expf(-z));
  }
}

__global__ void diag_kernel(float* out, float v) { out[0] = v; }

extern "C" void kernel_launch(void* const* d_in, const int* in_sizes, int n_in,
                              void* d_out, int out_size, void* d_ws, size_t ws_size,
                              hipStream_t stream) {
  const float* x   = (const float*)d_in[0];
  const int*   ei  = (const int*)d_in[1];
  const float* W1a = (const float*)d_in[2];
  const float* b1a = (const float*)d_in[3];
  const float* W2a = (const float*)d_in[4];
  const float* b2a = (const float*)d_in[5];
  const float* W1b = (const float*)d_in[6];
  const float* b1b = (const float*)d_in[7];
  const float* W2b = (const float*)d_in[8];
  const float* b2b = (const float*)d_in[9];
  const float* W3  = (const float*)d_in[10];
  const float* b3  = (const float*)d_in[11];
  const float* W4  = (const float*)d_in[12];
  const float* b4  = (const float*)d_in[13];

  // workspace layout (peak 34,211,968 B)
  char* ws = (char*)d_ws;
  short* Wp1T = (short*)(ws + 0);          //  262144 B [1024][128]
  short* Wp2T = (short*)(ws + 262144);     //  262144 B [512][256]
  short* BTf1 = (short*)(ws + 524288);     //  262144 B W2a^T fragment layout
  short* BTf2 = (short*)(ws + 786432);     //   65536 B W2b^T fragment layout
  short* A1B1 = (short*)(ws + 851968);     // 20480000 B [10000][1024] f16
  short* A2B2 = (short*)(ws + 851968);     // reuse (A1B1 dead): [10000][512]
  int*   Y1   = (int*)(ws + 21331968);     // 10240000 B [10000][256] fp32
  int*   Y2   = (int*)(ws + 21331968);     // reuse (Y1 dead): [10000][128] fp32
  int*   cnt  = (int*)(ws + 31571968);     //    40000 B
  int*   cur  = (int*)(ws + 31611968);     //    40000 B
  int*   sSrc = (int*)(ws + 31651968);     //  1280000 B
  int*   sDst = (int*)(ws + 32931968);     //  1280000 B

  if (ws_size < 34211968) {                // diagnostic: encode ws_size in the absmax error
    diag_kernel<<<1, 1, 0, stream>>>((float*)d_out, (float)ws_size);
    return;
  }

  // ---- counting sort by dst ----
  hipMemsetAsync(cnt, 0, 40000, stream);
  hist_kernel<<<1250, 256, 0, stream>>>(ei, cnt);
  scan_kernel<<<1, 1024, 0, stream>>>(cnt, cur);
  scatter_kernel<<<1250, 256, 0, stream>>>(ei, cur, sSrc, sDst);

  prep_weights<<<1664, 256, 0, stream>>>(W1a, W1b, W2a, W2b, Wp1T, Wp2T, BTf1, BTf2);

  // EdgeConv 1 (node_gemm: 16-row blocks -> 2500 blocks, 10/CU)
  node_gemm<128, 1><<<dim3(625, 4), 256, 0, stream>>>(x, Wp1T, b1a, 512, A1B1, 1024);
  hipMemsetAsync(Y1, 0, (size_t)NN * 256 * 4, stream);
  edge_gemm_pf<512, 256, 64><<<5000, 256, 0, stream>>>(A1B1, BTf1, b2a, sSrc, sDst, Y1);

  // EdgeConv 2 (node_gemm2: 1250 blocks, 5/CU; A2B2 overwrites dead A1B1)
  node_gemm<256, 1><<<dim3(625, 2), 256, 0, stream>>>((const float*)Y1, Wp2T, b1b, 256, A2B2, 512);
  hipMemsetAsync(Y2, 0, (size_t)NN * 128 * 4, stream);
  edge_gemm_pf<256, 128, 128><<<2500, 256, 0, stream>>>(A2B2, BTf2, b2b, sSrc, sDst, Y2);

  // Head
  head_kernel<<<NN, 64, 0, stream>>>((const float*)Y2, W3, b3, W4, b4, (float*)d_out);
}

// Round 20
// 363.106 us; speedup vs baseline: 1.0386x; 1.0386x over previous
//
#include <hip/hip_runtime.h>
#include <math.h>

#define NN 10000
#define NE 320000

typedef __attribute__((ext_vector_type(8))) _Float16 h8v;    // 8 f16 (4 VGPRs) MFMA frag
typedef __attribute__((ext_vector_type(4))) float f4v;       // MFMA accumulator

__device__ __forceinline__ short f2h(float f) {
  _Float16 h = (_Float16)f;            // v_cvt_f16_f32 (RNE)
  short s; __builtin_memcpy(&s, &h, 2); return s;
}
// relu(f16a + f16b) on 8 packed f16 lanes: native clang vector arithmetic lowers
// to 4x v_pk_add_f16 + 4x v_pk_max_f16 with FULL register-allocator freedom.
__device__ __forceinline__ uint4 cvt8(uint4 ua, uint4 ub) {
  h8v a, b;
  __builtin_memcpy(&a, &ua, 16);
  __builtin_memcpy(&b, &ub, 16);
  h8v r = a + b;
  r = __builtin_elementwise_max(r, (h8v)(_Float16)0.0f);
  uint4 o; __builtin_memcpy(&o, &r, 16);
  return o;
}

// lgkm-only barrier: orders all LDS traffic; leaves gather prefetches in flight.
__device__ __forceinline__ void barrier_lgkm_only() {
  asm volatile("s_waitcnt lgkmcnt(0)" ::: "memory");
  __builtin_amdgcn_s_barrier();
}

// ================= edge sort by dst (counting sort) =================
__global__ void hist_kernel(const int* __restrict__ ei, int* __restrict__ cnt) {
  int e = blockIdx.x * 256 + threadIdx.x;
  if (e < NE) atomicAdd(&cnt[ei[NE + e]], 1);
}

__global__ void __launch_bounds__(1024)
scan_kernel(const int* __restrict__ cnt, int* __restrict__ cur) {
  __shared__ int part[1024];
  const int t = threadIdx.x;
  const int base = t * 10;
  int local[10];
  int s = 0;
#pragma unroll
  for (int u = 0; u < 10; ++u) {
    int c = (base + u < NN) ? cnt[base + u] : 0;
    local[u] = s; s += c;
  }
  part[t] = s;
  __syncthreads();
  for (int off = 1; off < 1024; off <<= 1) {
    int v = part[t];
    int w = (t >= off) ? part[t - off] : 0;
    __syncthreads();
    part[t] = v + w;
    __syncthreads();
  }
  int excl = (t == 0) ? 0 : part[t - 1];
#pragma unroll
  for (int u = 0; u < 10; ++u)
    if (base + u < NN) cur[base + u] = excl + local[u];
}

__global__ void scatter_kernel(const int* __restrict__ ei, int* __restrict__ cur,
                               int* __restrict__ sSrc, int* __restrict__ sDst) {
  int e = blockIdx.x * 256 + threadIdx.x;
  if (e < NE) {
    int d = ei[NE + e];
    int p = atomicAdd(&cur[d], 1);
    sSrc[p] = ei[e];
    sDst[p] = d;
  }
}

// ================= prep: combined/transposed weights, fp32 -> f16 =================
// Round-20 change: index mappings inverted so consecutive LANES read consecutive
// INPUT addresses (coalesced loads; loads stall, stores don't). Writes become
// strided but are fire-and-forget. Same outputs:
//  Wp1T [1024][128] node-GEMM layout; Wp2T [512][256];
//  BTf1/BTf2 edge-GEMM fragment layout idx = (k>>5)*(NT*32) + n*32 + (k&31).
__global__ void prep_weights(const float* __restrict__ W1a, const float* __restrict__ W1b,
                             const float* __restrict__ W2a, const float* __restrict__ W2b,
                             short* __restrict__ Wp1T, short* __restrict__ Wp2T,
                             short* __restrict__ BTf1, short* __restrict__ BTf2) {
  int i = blockIdx.x * 256 + threadIdx.x;
  if (i < 131072) {                        // Wp1T: k = i>>10 (0..127), j = i&1023
    int k = i >> 10, j = i & 1023;
    float v;
    if (j < 512) v = W1a[k * 512 + j] - W1a[(k + 128) * 512 + j];     // coalesced in j
    else         v = W1a[(k + 128) * 512 + (j - 512)];                 // coalesced in j
    Wp1T[j * 128 + k] = f2h(v);
  } else if (i < 262144) {                 // Wp2T: k = t>>9 (0..255), j = t&511
    int t = i - 131072;
    int k = t >> 9, j = t & 511;
    float v;
    if (j < 256) v = W1b[k * 256 + j] - W1b[(k + 256) * 256 + j];
    else         v = W1b[(k + 256) * 256 + (j - 256)];
    Wp2T[j * 256 + k] = f2h(v);
  } else if (i < 393216) {                 // BTf1: k = t>>8 (0..511), n = t&255
    int t = i - 262144;
    int k = t >> 8, n = t & 255;
    BTf1[(k >> 5) * 8192 + n * 32 + (k & 31)] = f2h(W2a[k * 256 + n]);  // coalesced in n
  } else if (i < 425984) {                 // BTf2: k = t>>7 (0..255), n = t&127
    int t = i - 393216;
    int k = t >> 7, n = t & 127;
    BTf2[(k >> 5) * 4096 + n * 32 + (k & 31)] = f2h(W2b[k * 128 + n]);  // coalesced in n
  }
}

// ================= node GEMM: C[NN][Ntot](f16) = A[NN][K](fp32) @ BT^T + bias ===========
// Round-18 config (64-row blocks; MT=1 regressed +13us in round 19 via 4x B-panel
// L2 re-reads). C-write via padded LDS tile: 32 lanes store one 512B row of uint4.
template<int K>
__global__ void __launch_bounds__(256)
node_gemm(const float* __restrict__ A, const short* __restrict__ BT,
          const float* __restrict__ bias, int biasLen,
          short* __restrict__ C, int Ntot) {
  constexpr int CTP = 264;                  // LDS pitch (shorts): 16B rows + bank skew
  __shared__ short ct[64 * CTP];            // 33,792 B
  const int rowBase = blockIdx.x * 64;
  const int wave = threadIdx.x >> 6, lane = threadIdx.x & 63;
  const int colBase = blockIdx.y * 256 + wave * 64;
  const int lm = lane & 15, q = lane >> 4;
  f4v acc[4][4] = {};
  int arow[4];
#pragma unroll
  for (int mt = 0; mt < 4; ++mt) {
    int r = rowBase + mt * 16 + lm;
    arow[mt] = r < NN ? r : NN - 1;        // clamp; stores guarded below
  }
  for (int kk = 0; kk < K; kk += 32) {
    const int k = kk + q * 8;
    h8v aF[4], bF[4];
#pragma unroll
    for (int mt = 0; mt < 4; ++mt) {
      const float4* ap = (const float4*)(A + (size_t)arow[mt] * K + k);
      float4 x0 = ap[0], x1 = ap[1];
      h8v t;
      t[0] = (_Float16)x0.x; t[1] = (_Float16)x0.y; t[2] = (_Float16)x0.z; t[3] = (_Float16)x0.w;
      t[4] = (_Float16)x1.x; t[5] = (_Float16)x1.y; t[6] = (_Float16)x1.z; t[7] = (_Float16)x1.w;
      aF[mt] = t;
    }
#pragma unroll
    for (int nt = 0; nt < 4; ++nt)
      bF[nt] = *(const h8v*)(BT + (size_t)(colBase + nt * 16 + lm) * K + k);
#pragma unroll
    for (int mt = 0; mt < 4; ++mt)
#pragma unroll
      for (int nt = 0; nt < 4; ++nt)
        acc[mt][nt] = __builtin_amdgcn_mfma_f32_16x16x32_f16(aF[mt], bF[nt], acc[mt][nt], 0, 0, 0);
  }
  // acc -> LDS tile (wave's 64-col slice)
  const int wc = wave * 64;
#pragma unroll
  for (int nt = 0; nt < 4; ++nt) {
    int col = colBase + nt * 16 + lm;
    float bv = (col < biasLen) ? bias[col] : 0.0f;
#pragma unroll
    for (int mt = 0; mt < 4; ++mt) {
#pragma unroll
      for (int i = 0; i < 4; ++i)
        ct[(mt * 16 + q * 4 + i) * CTP + wc + nt * 16 + lm] = f2h(acc[mt][nt][i] + bv);
    }
  }
  __syncthreads();
  // coalesced stores: 32 lanes cover one 512B row contiguously
  const int cb0 = blockIdx.y * 256;
  const int tid = threadIdx.x;
#pragma unroll
  for (int it = 0; it < 8; ++it) {
    int lr = it * 8 + (tid >> 5);
    int row = rowBase + lr;
    int chunk = tid & 31;                   // 32 x 16B = 512B per row
    if (row < NN)
      *(uint4*)(C + (size_t)row * Ntot + cb0 + chunk * 8) =
          *(const uint4*)(&ct[lr * CTP + chunk * 8]);
  }
}

// ================= edge GEMM: f16, 256-thread (4-wave) blocks at (256,3) ==============
// Round-13 config exactly (edge1 ~127us; structural floor — occupancy directions,
// prefetch depth, and barrier semantics all falsified in rounds 12/16/17).
template<int K, int NT, int ROWS>
__global__ void __launch_bounds__(256, 3)
edge_gemm_pf(const short* __restrict__ AB, const short* __restrict__ BTf,
             const float* __restrict__ bias,
             const int* __restrict__ sSrc, const int* __restrict__ sDst,
             int* __restrict__ y) {
  constexpr int KT = 64;            // k-tile
  constexpr int KTP = 72;           // LDS pitch (shorts): breaks bank alignment, keeps 16B
  constexpr int TILES = K / KT;
  constexpr int NCG = NT / 64;      // col-groups (4 or 2)
  constexpr int NRG = 4 / NCG;      // row-groups (1 or 2)
  constexpr int CH = ROWS / 32;     // staged chunks per thread (2 or 4)
  constexpr int NTL = 4;            // 64 cols per wave
  static_assert(ROWS == 64 * NRG, "geometry");
  __shared__ __align__(16) short hA[2][ROWS * KTP];
  __shared__ int srcS[ROWS], dstS[ROWS];
  __shared__ int segDst[2][64];     // dst node per segment, per row-group
  __shared__ int segAtm[2][64];     // 1 = boundary dst (atomic), 0 = interior (store)
  __shared__ __align__(4) unsigned char rowSidC[ROWS]; // per-row segment id within group
  __shared__ int segD[2];

  const int tid = threadIdx.x;
  const int eBase = blockIdx.x * ROWS;
  const int wave = tid >> 6, lane = tid & 63, lm = lane & 15, q = lane >> 4;
  const int cg = wave % NCG, rg = wave / NCG;
  const int cBase = cg * 64;
  const int rg64 = rg * 64;

  if (tid < ROWS) { srcS[tid] = sSrc[eBase + tid]; dstS[tid] = sDst[eBase + tid]; }
  __syncthreads();

  // per-thread staging coords: CH chunks (rows r0+32c), fixed column chunk kc0
  const int r0 = tid >> 3, kc0 = (tid & 7) * 8;
  size_t dO[CH], sO[CH];
#pragma unroll
  for (int c = 0; c < CH; ++c) {
    dO[c] = (size_t)dstS[r0 + 32 * c] * (2 * K) + kc0;
    sO[c] = (size_t)srcS[r0 + 32 * c] * (2 * K) + K + kc0;
  }

  // prologue: issue tile-0 gather prefetch FIRST (latency hidden under table build)
  uint4 av[CH], bv[CH];
#pragma unroll
  for (int c = 0; c < CH; ++c) {
    av[c] = *(const uint4*)(AB + dO[c]);
    bv[c] = *(const uint4*)(AB + sO[c]);
  }

  // ---- waves 0..NRG-1: build per-row-group segment tables (consumed in epilogue;
  // visibility guaranteed by the main-loop barriers) ----
  if (tid < NRG * 64) {
    const int w = tid >> 6;          // row-group
    const int r = tid & 63;          // row within group
    const int row = tid;
    int d = dstS[row];
    int prev = (r == 0) ? -1 : dstS[row - 1];
    bool flag = (r == 0) || (d != prev);
    unsigned long long mask = __ballot(flag);
    int Dtot = __popcll(mask);
    int sid = __popcll(mask & (0xFFFFFFFFFFFFFFFFull >> (63 - r))) - 1;
    rowSidC[row] = (unsigned char)sid;
    if (r == 0) segD[w] = Dtot;
    if (flag) {
      int prevOut = (w > 0) ? dstS[w * 64 - 1]
                            : ((eBase > 0) ? sDst[eBase - 1] : -1);
      int nextOut = (w < NRG - 1) ? dstS[(w + 1) * 64]
                                  : ((eBase + ROWS < NE) ? sDst[eBase + ROWS] : -1);
      bool atm = false;
      if (sid == 0 && prevOut == d) atm = true;
      if (sid == Dtot - 1 && nextOut == d) atm = true;
      segDst[w][sid] = d;
      segAtm[w][sid] = atm ? 1 : 0;
    }
  }

  f4v acc[4][NTL] = {};

  for (int t = 0; t < TILES; ++t) {
    // 1. issue s=0 bF loads (fly during convert + barrier)
    h8v bF0[NTL];
#pragma unroll
    for (int nt = 0; nt < NTL; ++nt)
      bF0[nt] = *(const h8v*)(BTf + (size_t)(t * 2) * (NT * 32) +
                              (cBase + nt * 16 + lm) * 32 + q * 8);
    // 2. convert prefetched gathers -> LDS (double-buffered); packed-f16 ops
    short* hbuf = &hA[t & 1][0];
#pragma unroll
    for (int c = 0; c < CH; ++c)
      *(uint4*)(&hbuf[(r0 + 32 * c) * KTP + kc0]) = cvt8(av[c], bv[c]);
    // 3. prefetch next tile's gathers (stay in flight across the lgkm-only barrier)
    if (t + 1 < TILES) {
      const int kn = (t + 1) * KT;
#pragma unroll
      for (int c = 0; c < CH; ++c) {
        av[c] = *(const uint4*)(AB + dO[c] + kn);
        bv[c] = *(const uint4*)(AB + sO[c] + kn);
      }
    }
    barrier_lgkm_only();
    // 4a. s=0 MFMA: aF per-mt from LDS, bF0 from regs
    {
      const int kl = q * 8;
      __builtin_amdgcn_s_setprio(1);
#pragma unroll
      for (int mt = 0; mt < 4; ++mt) {
        h8v aF = *(const h8v*)(&hbuf[(rg64 + mt * 16 + lm) * KTP + kl]);
#pragma unroll
        for (int nt = 0; nt < NTL; ++nt)
          acc[mt][nt] = __builtin_amdgcn_mfma_f32_16x16x32_f16(aF, bF0[nt], acc[mt][nt], 0, 0, 0);
      }
      __builtin_amdgcn_s_setprio(0);
    }
    // 4b. s=1: load bF1 here (keeps bF register footprint at NTL)
    {
      h8v bF1[NTL];
#pragma unroll
      for (int nt = 0; nt < NTL; ++nt)
        bF1[nt] = *(const h8v*)(BTf + (size_t)(t * 2 + 1) * (NT * 32) +
                                (cBase + nt * 16 + lm) * 32 + q * 8);
      const int kl = 32 + q * 8;
      __builtin_amdgcn_s_setprio(1);
#pragma unroll
      for (int mt = 0; mt < 4; ++mt) {
        h8v aF = *(const h8v*)(&hbuf[(rg64 + mt * 16 + lm) * KTP + kl]);
#pragma unroll
        for (int nt = 0; nt < NTL; ++nt)
          acc[mt][nt] = __builtin_amdgcn_mfma_f32_16x16x32_f16(aF, bF1[nt], acc[mt][nt], 0, 0, 0);
      }
      __builtin_amdgcn_s_setprio(0);
    }
  }

  // ---- epilogue: segmented max per column within this wave's row-group ----
  const int D = segD[rg];
  int sid[4][4];
#pragma unroll
  for (int mt = 0; mt < 4; ++mt) {
    unsigned pk = *(const unsigned*)(&rowSidC[rg64 + mt * 16 + q * 4]);  // 4B aligned
#pragma unroll
    for (int i = 0; i < 4; ++i) sid[mt][i] = (int)((pk >> (8 * i)) & 255u);
  }
#pragma unroll
  for (int nt = 0; nt < NTL; ++nt) {
    const int col = cBase + nt * 16 + lm;
    const float bvv = bias[col];
    for (int s = 0; s < D; ++s) {
      float m = -1e30f;
#pragma unroll
      for (int mt = 0; mt < 4; ++mt)
#pragma unroll
        for (int i = 0; i < 4; ++i)
          m = fmaxf(m, sid[mt][i] == s ? acc[mt][nt][i] : -1e30f);
      // reduce across the 4 q-lanes holding this column
      m = fmaxf(m, __shfl_xor(m, 16));
      m = fmaxf(m, __shfl_xor(m, 32));
      if (q == 0) {
        float v = m + bvv;
        int* addr = &y[(size_t)segDst[rg][s] * NT + col];
        if (segAtm[rg][s]) {
          if (v > 0.f) atomicMax(addr, __float_as_int(v));
        } else {
          *addr = __float_as_int(fmaxf(v, 0.f));   // group owns this dst: plain store
        }
      }
    }
  }
}

// ================= head: one wave per node =================
__global__ void __launch_bounds__(64)
head_kernel(const float* __restrict__ y2, const float* __restrict__ W3,
            const float* __restrict__ b3, const float* __restrict__ W4,
            const float* __restrict__ b4, float* __restrict__ out) {
  const int n = blockIdx.x, j = threadIdx.x;
  const float* yr = y2 + (size_t)n * 128;
  float acc = 0.f;
#pragma unroll
  for (int k = 0; k < 128; ++k) acc += yr[k] * W3[k * 64 + j];
  acc += b3[j];
  float h = acc > 0.f ? acc : 0.f;
  float p = h * W4[j];
#pragma unroll
  for (int off = 32; off; off >>= 1) p += __shfl_down(p, off);
  if (j == 0) {
    float z = p + b4[0];
    out[n] = 1.f / (1.f + expf(-z));
  }
}

__global__ void diag_kernel(float* out, float v) { out[0] = v; }

extern "C" void kernel_launch(void* const* d_in, const int* in_sizes, int n_in,
                              void* d_out, int out_size, void* d_ws, size_t ws_size,
                              hipStream_t stream) {
  const float* x   = (const float*)d_in[0];
  const int*   ei  = (const int*)d_in[1];
  const float* W1a = (const float*)d_in[2];
  const float* b1a = (const float*)d_in[3];
  const float* W2a = (const float*)d_in[4];
  const float* b2a = (const float*)d_in[5];
  const float* W1b = (const float*)d_in[6];
  const float* b1b = (const float*)d_in[7];
  const float* W2b = (const float*)d_in[8];
  const float* b2b = (const float*)d_in[9];
  const float* W3  = (const float*)d_in[10];
  const float* b3  = (const float*)d_in[11];
  const float* W4  = (const float*)d_in[12];
  const float* b4  = (const float*)d_in[13];

  // workspace layout (peak 34,211,968 B)
  char* ws = (char*)d_ws;
  short* Wp1T = (short*)(ws + 0);          //  262144 B [1024][128]
  short* Wp2T = (short*)(ws + 262144);     //  262144 B [512][256]
  short* BTf1 = (short*)(ws + 524288);     //  262144 B W2a^T fragment layout
  short* BTf2 = (short*)(ws + 786432);     //   65536 B W2b^T fragment layout
  short* A1B1 = (short*)(ws + 851968);     // 20480000 B [10000][1024] f16
  short* A2B2 = (short*)(ws + 851968);     // reuse (A1B1 dead): [10000][512]
  int*   Y1   = (int*)(ws + 21331968);     // 10240000 B [10000][256] fp32
  int*   Y2   = (int*)(ws + 21331968);     // reuse (Y1 dead): [10000][128] fp32
  int*   cnt  = (int*)(ws + 31571968);     //    40000 B
  int*   cur  = (int*)(ws + 31611968);     //    40000 B
  int*   sSrc = (int*)(ws + 31651968);     //  1280000 B
  int*   sDst = (int*)(ws + 32931968);     //  1280000 B

  if (ws_size < 34211968) {                // diagnostic: encode ws_size in the absmax error
    diag_kernel<<<1, 1, 0, stream>>>((float*)d_out, (float)ws_size);
    return;
  }

  // ---- counting sort by dst ----
  hipMemsetAsync(cnt, 0, 40000, stream);
  hist_kernel<<<1250, 256, 0, stream>>>(ei, cnt);
  scan_kernel<<<1, 1024, 0, stream>>>(cnt, cur);
  scatter_kernel<<<1250, 256, 0, stream>>>(ei, cur, sSrc, sDst);

  prep_weights<<<1664, 256, 0, stream>>>(W1a, W1b, W2a, W2b, Wp1T, Wp2T, BTf1, BTf2);

  // EdgeConv 1
  node_gemm<128><<<dim3(157, 4), 256, 0, stream>>>(x, Wp1T, b1a, 512, A1B1, 1024);
  hipMemsetAsync(Y1, 0, (size_t)NN * 256 * 4, stream);
  edge_gemm_pf<512, 256, 64><<<5000, 256, 0, stream>>>(A1B1, BTf1, b2a, sSrc, sDst, Y1);

  // EdgeConv 2 (A2B2 overwrites dead A1B1; Y2 memset AFTER node_gemm reads aliased Y1)
  node_gemm<256><<<dim3(157, 2), 256, 0, stream>>>((const float*)Y1, Wp2T, b1b, 256, A2B2, 512);
  hipMemsetAsync(Y2, 0, (size_t)NN * 128 * 4, stream);
  edge_gemm_pf<256, 128, 128><<<2500, 256, 0, stream>>>(A2B2, BTf2, b2b, sSrc, sDst, Y2);

  // Head
  head_kernel<<<NN, 64, 0, stream>>>((const float*)Y2, W3, b3, W4, b4, (float*)d_out);
}